// Round 2
// baseline (3331.743 us; speedup 1.0000x reference)
//
#include <hip/hip_runtime.h>
#include <stdint.h>

#define T_LEN 256
#define BATCH 64
#define EDIM  512
#define HDIM  256      // hidden per direction
#define GDIM  1024     // 4*HDIM
#define KTAG  7
#define NEGV  -10000.0f

using u16 = unsigned short;
using u32 = unsigned int;

typedef short bf16x8 __attribute__((ext_vector_type(8)));
typedef float f32x4  __attribute__((ext_vector_type(4)));

__device__ __forceinline__ float bflo(u32 u) { return __uint_as_float(u << 16); }
__device__ __forceinline__ float bfhi(u32 u) { return __uint_as_float(u & 0xffff0000u); }
__device__ __forceinline__ float bf2f(u16 u) { return __uint_as_float(((u32)u) << 16); }
__device__ __forceinline__ u16 f2bf(float f) {
    u32 x = __float_as_uint(f);
    u32 r = x + 0x7fffu + ((x >> 16) & 1u);   // round-to-nearest-even
    return (u16)(r >> 16);
}
__device__ __forceinline__ u32 pack2(float a, float b) {
    return (u32)f2bf(a) | ((u32)f2bf(b) << 16);
}

// ---------------- embedding gather+convert: x[tb][e] = bf16(emb[sent[tb]][e]) ----------------
__global__ __launch_bounds__(64) void embed_k(const int* __restrict__ sent,
                                              const float* __restrict__ emb,
                                              u16* __restrict__ X) {
    int tb = blockIdx.x;
    int tok = sent[tb];
    const float4* src = (const float4*)(emb + (size_t)tok * EDIM);
    float4 a = src[threadIdx.x * 2];
    float4 b = src[threadIdx.x * 2 + 1];
    uint4 o;
    o.x = pack2(a.x, a.y); o.y = pack2(a.z, a.w);
    o.z = pack2(b.x, b.y); o.w = pack2(b.z, b.w);
    ((uint4*)(X + (size_t)tb * EDIM))[threadIdx.x] = o;
}

// ---------------- convert w_ih f32 -> bf16, same layout [2][2][1024][512] ----------------
__global__ __launch_bounds__(256) void conv_wih(const float* __restrict__ W,
                                                u16* __restrict__ WB) {
    int g = blockIdx.x * 256 + threadIdx.x;          // 262144 groups of 8
    const float4* src = (const float4*)(W + (size_t)g * 8);
    float4 a = src[0], b = src[1];
    uint4 o;
    o.x = pack2(a.x, a.y); o.y = pack2(a.z, a.w);
    o.z = pack2(b.x, b.y); o.w = pack2(b.z, b.w);
    *(uint4*)(WB + (size_t)g * 8) = o;
}

// ------------- repack+convert w_hh [4][1024][256] f32 -> [4][32][1024][8] bf16 -------------
__global__ __launch_bounds__(256) void repack_whh(const float* __restrict__ Whh,
                                                  u16* __restrict__ WT) {
    int g = blockIdx.x * 256 + threadIdx.x;     // 4*32*1024 = 131072 groups of 8
    int ld  = g >> 15;                          // layer*2+dir
    int rem = g & 32767;
    int kb  = rem >> 10;                        // 0..31
    int j   = rem & 1023;                       // gate row
    const float4* src = (const float4*)(Whh + ((size_t)(ld * GDIM + j)) * HDIM + kb * 8);
    float4 a = src[0], b = src[1];
    uint4 o;
    o.x = pack2(a.x, a.y); o.y = pack2(a.z, a.w);
    o.z = pack2(b.x, b.y); o.w = pack2(b.z, b.w);
    *(uint4*)(WT + (size_t)g * 8) = o;
}

// ------------- xg = x @ w_ih^T + b_ih + b_hh  (MFMA bf16, wave computes 16x64) -------------
__global__ __launch_bounds__(256) void gemm_xg(const u16* __restrict__ A,    // [16384][512] bf16
                                               const u16* __restrict__ W,    // [2][1024][512] bf16
                                               const float* __restrict__ Bih,// [2][1024] f32
                                               const float* __restrict__ Bhh,
                                               u16* __restrict__ XG) {       // [2][16384][1024] bf16
    const int d    = blockIdx.y;
    const int lane = threadIdx.x & 63;
    const int wv   = threadIdx.x >> 6;
    const int wid  = blockIdx.x * 4 + wv;       // 0..16383
    const int nj   = wid >> 10;                 // 0..15  (n-tile of 64)
    const int mi   = wid & 1023;                // 0..1023 (m-tile of 16)
    const int l15  = lane & 15;
    const int quad = lane >> 4;

    const u16* Wd  = W + (size_t)d * GDIM * EDIM;
    const u16* Ap  = A  + (size_t)(mi * 16 + l15) * EDIM + quad * 8;
    const u16* Bp0 = Wd + (size_t)(nj * 64 +  0 + l15) * EDIM + quad * 8;
    const u16* Bp1 = Wd + (size_t)(nj * 64 + 16 + l15) * EDIM + quad * 8;
    const u16* Bp2 = Wd + (size_t)(nj * 64 + 32 + l15) * EDIM + quad * 8;
    const u16* Bp3 = Wd + (size_t)(nj * 64 + 48 + l15) * EDIM + quad * 8;

    f32x4 acc0 = {0.f,0.f,0.f,0.f}, acc1 = acc0, acc2 = acc0, acc3 = acc0;
    #pragma unroll 4
    for (int kk = 0; kk < 16; ++kk) {
        bf16x8 a  = *(const bf16x8*)(Ap  + kk * 32);
        bf16x8 b0 = *(const bf16x8*)(Bp0 + kk * 32);
        bf16x8 b1 = *(const bf16x8*)(Bp1 + kk * 32);
        bf16x8 b2 = *(const bf16x8*)(Bp2 + kk * 32);
        bf16x8 b3 = *(const bf16x8*)(Bp3 + kk * 32);
        acc0 = __builtin_amdgcn_mfma_f32_16x16x32_bf16(a, b0, acc0, 0, 0, 0);
        acc1 = __builtin_amdgcn_mfma_f32_16x16x32_bf16(a, b1, acc1, 0, 0, 0);
        acc2 = __builtin_amdgcn_mfma_f32_16x16x32_bf16(a, b2, acc2, 0, 0, 0);
        acc3 = __builtin_amdgcn_mfma_f32_16x16x32_bf16(a, b3, acc3, 0, 0, 0);
    }

    u16* xgd = XG + (size_t)d * ((size_t)16384 * GDIM);
    const int row0 = mi * 16 + quad * 4;        // C/D: col=lane&15, row=(lane>>4)*4+reg
    f32x4 accs[4] = {acc0, acc1, acc2, acc3};
    #pragma unroll
    for (int t = 0; t < 4; ++t) {
        int col = nj * 64 + t * 16 + l15;
        float bias = Bih[d * GDIM + col] + Bhh[d * GDIM + col];
        #pragma unroll
        for (int r = 0; r < 4; ++r)
            xgd[(size_t)(row0 + r) * GDIM + col] = f2bf(accs[t][r] + bias);
    }
}

// ------------- recurrent scan: one block per (batch, dir); thread j = gate j -------------
__global__ __launch_bounds__(1024) void lstm_scan(const u16* __restrict__ XG,   // [2][16384][1024] bf16
                                                  const u16* __restrict__ WT,   // [2][32][1024][8] bf16
                                                  const float* __restrict__ H0, // [2][64][256] f32
                                                  const float* __restrict__ C0,
                                                  u16* __restrict__ XOUT) {     // [16384][512] bf16
    const int b = blockIdx.x & 63;
    const int d = blockIdx.x >> 6;
    const int j = threadIdx.x;

    __shared__ float act[GDIM];
    __shared__ __align__(16) float hsh[HDIM];

    const uint4* wt = (const uint4*)(WT + (size_t)d * (32 * GDIM * 8));

    float c = 0.0f;
    if (j < HDIM) {
        hsh[j] = H0[(d * BATCH + b) * HDIM + j];
        c      = C0[(d * BATCH + b) * HDIM + j];
    }
    __syncthreads();

    const u16* xgp = XG + (size_t)d * ((size_t)16384 * GDIM) + (size_t)b * GDIM + j;
    const float4* h4 = (const float4*)hsh;

    for (int s = 0; s < T_LEN; ++s) {
        int t = d ? (T_LEN - 1 - s) : s;
        float g = bf2f(xgp[(size_t)t * (BATCH * GDIM)]);
        #pragma unroll 8
        for (int kk = 0; kk < 32; ++kk) {
            uint4  w  = wt[kk * GDIM + j];    // bf16 w_hh[j][8kk..8kk+7], coalesced
            float4 ha = h4[2 * kk];           // LDS broadcast (uniform addr)
            float4 hb = h4[2 * kk + 1];
            g = fmaf(bflo(w.x), ha.x, g); g = fmaf(bfhi(w.x), ha.y, g);
            g = fmaf(bflo(w.y), ha.z, g); g = fmaf(bfhi(w.y), ha.w, g);
            g = fmaf(bflo(w.z), hb.x, g); g = fmaf(bfhi(w.z), hb.y, g);
            g = fmaf(bflo(w.w), hb.z, g); g = fmaf(bfhi(w.w), hb.w, g);
        }
        float a = (j >= 2 * HDIM && j < 3 * HDIM) ? tanhf(g)              // g-gate
                                                  : 1.0f / (1.0f + expf(-g));
        act[j] = a;
        __syncthreads();                       // dot-reads of hsh done; act visible
        if (j < HDIM) {
            float iv = act[j], fv = act[HDIM + j], gv = act[2 * HDIM + j], ov = act[3 * HDIM + j];
            c = fv * c + iv * gv;
            float h = ov * tanhf(c);
            hsh[j] = h;
            XOUT[(size_t)(t * BATCH + b) * EDIM + d * HDIM + j] = f2bf(h);
        }
        __syncthreads();                       // new hsh visible for next step
    }
}

// ------------- feats[tb][k] = x[tb] . w_out[k] + b_out[k]  (one wave per tb) -------------
__global__ __launch_bounds__(64) void feats_k(const u16* __restrict__ X,      // [16384][512] bf16
                                              const float* __restrict__ Wout, // [7][512] f32
                                              const float* __restrict__ Bout, // [7] f32
                                              float* __restrict__ F) {        // [16384][8] f32
    int tb = blockIdx.x, lane = threadIdx.x;
    uint4 xv = ((const uint4*)(X + (size_t)tb * EDIM))[lane];   // 8 bf16 of x
    float xf[8];
    xf[0] = bflo(xv.x); xf[1] = bfhi(xv.x); xf[2] = bflo(xv.y); xf[3] = bfhi(xv.y);
    xf[4] = bflo(xv.z); xf[5] = bfhi(xv.z); xf[6] = bflo(xv.w); xf[7] = bfhi(xv.w);
    #pragma unroll
    for (int k = 0; k < KTAG; ++k) {
        const float4* wp = (const float4*)(Wout + (size_t)k * EDIM) + lane * 2;
        float4 wa = wp[0], wb = wp[1];
        float p = 0.0f;
        p = fmaf(xf[0], wa.x, p); p = fmaf(xf[1], wa.y, p);
        p = fmaf(xf[2], wa.z, p); p = fmaf(xf[3], wa.w, p);
        p = fmaf(xf[4], wb.x, p); p = fmaf(xf[5], wb.y, p);
        p = fmaf(xf[6], wb.z, p); p = fmaf(xf[7], wb.w, p);
        #pragma unroll
        for (int off = 32; off > 0; off >>= 1) p += __shfl_xor(p, off, 64);
        if (lane == 0) F[tb * 8 + k] = p + Bout[k];
    }
}

// ------------- Viterbi: one wave, lane = batch; sequential over T -------------
__global__ __launch_bounds__(64) void viterbi_k(const float* __restrict__ F,
                                                const float* __restrict__ Trans, // [7][7] next,prev f32
                                                int* __restrict__ BPS,           // [256][64][8]
                                                float* __restrict__ OUT) {       // 16448 floats
    int b = threadIdx.x;
    float tr[KTAG][KTAG];
    #pragma unroll
    for (int n = 0; n < KTAG; ++n)
        #pragma unroll
        for (int p = 0; p < KTAG; ++p)
            tr[n][p] = Trans[n * KTAG + p];

    float v[KTAG];
    #pragma unroll
    for (int k = 0; k < KTAG; ++k) v[k] = (k == 5) ? 0.0f : NEGV;  // START=5

    for (int t = 0; t < T_LEN; ++t) {
        int base = (t * BATCH + b) * 8;
        float nv[KTAG];
        #pragma unroll
        for (int n = 0; n < KTAG; ++n) {
            float best = v[0] + tr[n][0]; int bi = 0;
            #pragma unroll
            for (int p = 1; p < KTAG; ++p) {
                float s = v[p] + tr[n][p];
                if (s > best) { best = s; bi = p; }   // strict > == np.argmax first-max
            }
            BPS[base + n] = bi;
            nv[n] = best + F[base + n];
        }
        #pragma unroll
        for (int n = 0; n < KTAG; ++n) v[n] = nv[n];
    }
    float bs = v[0] + tr[6][0]; int tag = 0;          // STOP=6
    #pragma unroll
    for (int k = 1; k < KTAG; ++k) {
        float s = v[k] + tr[6][k];
        if (s > bs) { bs = s; tag = k; }
    }
    OUT[T_LEN * BATCH + b] = bs;                      // path_score [B]
    for (int t = T_LEN - 1; t >= 0; --t) {
        OUT[(size_t)b * T_LEN + t] = (float)tag;      // best_path [B][T]
        tag = BPS[(t * BATCH + b) * 8 + tag];
    }
}

extern "C" void kernel_launch(void* const* d_in, const int* in_sizes, int n_in,
                              void* d_out, int out_size, void* d_ws, size_t ws_size,
                              hipStream_t stream) {
    const int*   sent  = (const int*)d_in[0];
    const float* emb   = (const float*)d_in[1];   // [50000][512]
    const float* w_ih  = (const float*)d_in[2];   // [2][2][1024][512]
    const float* w_hh  = (const float*)d_in[3];   // [2][2][1024][256]
    const float* b_ih  = (const float*)d_in[4];   // [2][2][1024]
    const float* b_hh  = (const float*)d_in[5];
    const float* w_out = (const float*)d_in[6];   // [7][512]
    const float* b_out = (const float*)d_in[7];   // [7]
    const float* trans = (const float*)d_in[8];   // [7][7]
    const float* h0    = (const float*)d_in[9];   // [4][64][256]
    const float* c0    = (const float*)d_in[10];
    float* out = (float*)d_out;

    char* ws = (char*)d_ws;
    u16*   xg    = (u16*)(ws);                       // 64 MB  [2][16384][1024] bf16
    u16*   x     = (u16*)(ws + 67108864);            // 16 MB  [16384][512] bf16 (in-place across layers)
    u16*   wihB  = (u16*)(ws + 67108864 + 16777216); // 4 MB   bf16 w_ih
    u16*   wT    = (u16*)(ws + 67108864 + 20971520); // 2 MB   bf16 repacked w_hh
    float* feats = (float*)(ws + 67108864 + 23068672);  // 512 KB
    int*   bps   = (int*)(ws + 67108864 + 23592960);    // 512 KB
    // total = 91,226,112 bytes (~87 MB)

    embed_k<<<16384, 64, 0, stream>>>(sent, emb, x);
    conv_wih<<<1024, 256, 0, stream>>>(w_ih, wihB);
    repack_whh<<<512, 256, 0, stream>>>(w_hh, wT);

    for (int l = 0; l < 2; ++l) {
        gemm_xg<<<dim3(4096, 2), 256, 0, stream>>>(
            x, wihB + (size_t)l * 2 * GDIM * EDIM,
            b_ih + (size_t)l * 2 * GDIM, b_hh + (size_t)l * 2 * GDIM, xg);
        // gemm_xg has fully consumed x before lstm_scan overwrites it (stream-ordered)
        lstm_scan<<<128, 1024, 0, stream>>>(
            xg, wT + (size_t)l * 2 * 32 * GDIM * 8,
            h0 + (size_t)l * 2 * BATCH * HDIM, c0 + (size_t)l * 2 * BATCH * HDIM, x);
    }

    feats_k<<<16384, 64, 0, stream>>>(x, w_out, b_out, feats);
    viterbi_k<<<1, 64, 0, stream>>>(feats, trans, bps, out);
}